// Round 9
// baseline (125.073 us; speedup 1.0000x reference)
//
#include <hip/hip_runtime.h>
#include <stdint.h>

#define RES_DIM 8192
#define BATCH   128
#define NNZ     1342177
#define LEAK    0.6f
#define BIAS    1.6f

#define CONV_BLOCKS 1024                          // (RES_DIM/32) * (BATCH/32)
#define BND_THREADS ((NNZ + 3) / 4)               // 335545
#define BND_BLOCKS  ((BND_THREADS + 255) / 256)   // 1311

// ---------------------------------------------------------------------------
// helpers
// ---------------------------------------------------------------------------
__device__ __forceinline__ float fast_tanh(float x) {
    float e = __expf(2.0f * x);
    return 1.0f - 2.0f / (e + 1.0f);
}

__device__ __forceinline__ uint32_t f32_to_bf16_rne(float f) {
    uint32_t u = __float_as_uint(f);
    return (u + 0x7fffu + ((u >> 16) & 1u)) >> 16;
}

// ---------------------------------------------------------------------------
// Kernel 1 (fused prep): conv (bf16-pack transpose) + rowptr boundary detect
// ---------------------------------------------------------------------------
__global__ __launch_bounds__(256) void prep_kernel(
    const float* __restrict__ in, uint32_t* __restrict__ st2,
    const int* __restrict__ rows, int* __restrict__ row_start) {
    if (blockIdx.x < CONV_BLOCKS) {
        __shared__ float tile[32][33];
        const int bx = blockIdx.x & 255;     // r-tile
        const int by = blockIdx.x >> 8;      // b-tile
        const int tx = threadIdx.x & 31, ty = threadIdx.x >> 5;  // 32x8
        const int r0 = bx * 32, b0 = by * 32;
#pragma unroll
        for (int j = 0; j < 32; j += 8)
            tile[ty + j][tx] = in[(size_t)(b0 + ty + j) * RES_DIM + r0 + tx];
        __syncthreads();
#pragma unroll
        for (int i = threadIdx.x; i < 512; i += 256) {   // 32 r x 16 pairs
            int rl = i >> 4, pl = i & 15;
            uint32_t lo = f32_to_bf16_rne(tile[2 * pl + 0][rl]);
            uint32_t hi = f32_to_bf16_rne(tile[2 * pl + 1][rl]);
            st2[(size_t)(r0 + rl) * 64 + (b0 >> 1) + pl] = lo | (hi << 16);
        }
    } else {
        const int t  = (blockIdx.x - CONV_BLOCKS) * 256 + threadIdx.x;
        const int k4 = t * 4;
        if (k4 >= NNZ) return;
        if (k4 + 4 <= NNZ) {                 // full int4 (NNZ % 4 == 1)
            const int4 R = *(const int4*)(rows + k4);
            if (k4 == 0)
                for (int r = 0; r <= R.x; ++r) row_start[r] = 0;
            const int rn = rows[k4 + 4];
            for (int r = R.x + 1; r <= R.y; ++r) row_start[r] = k4 + 1;
            for (int r = R.y + 1; r <= R.z; ++r) row_start[r] = k4 + 2;
            for (int r = R.z + 1; r <= R.w; ++r) row_start[r] = k4 + 3;
            for (int r = R.w + 1; r <= rn;  ++r) row_start[r] = k4 + 4;
        } else {                             // k4 == NNZ-1 exactly
            const int r1 = rows[k4];
            for (int r = r1 + 1; r <= RES_DIM; ++r) row_start[r] = NNZ;
        }
    }
}

// ---------------------------------------------------------------------------
// Kernel 2: spmm + fused epilogue (identical to round 8).
// ---------------------------------------------------------------------------
#define FMA8(G, v)                                              \
    do {                                                        \
        a0 = fmaf(v, __uint_as_float((G).x << 16), a0);         \
        a1 = fmaf(v, __uint_as_float((G).x & 0xffff0000u), a1); \
        a2 = fmaf(v, __uint_as_float((G).y << 16), a2);         \
        a3 = fmaf(v, __uint_as_float((G).y & 0xffff0000u), a3); \
        a4 = fmaf(v, __uint_as_float((G).z << 16), a4);         \
        a5 = fmaf(v, __uint_as_float((G).z & 0xffff0000u), a5); \
        a6 = fmaf(v, __uint_as_float((G).w << 16), a6);         \
        a7 = fmaf(v, __uint_as_float((G).w & 0xffff0000u), a7); \
    } while (0)

#define LOADCV(s, u)                                            \
    do {                                                        \
        const int base_ = ka + ((u) << 4) + 4 * g;              \
        C##s = *(const int4*)(cols + base_);                    \
        V##s = *(const float4*)(vals + base_);                  \
    } while (0)

#define LOADG(s)                                                              \
    do {                                                                      \
        G##s##0 = *(const uint4*)(stb + (((uint32_t)C##s.x << 8) + joff));    \
        G##s##1 = *(const uint4*)(stb + (((uint32_t)C##s.y << 8) + joff));    \
        G##s##2 = *(const uint4*)(stb + (((uint32_t)C##s.z << 8) + joff));    \
        G##s##3 = *(const uint4*)(stb + (((uint32_t)C##s.w << 8) + joff));    \
    } while (0)

#define CONS_T(s)                                               \
    do {                                                        \
        FMA8(G##s##0, Vt.x);                                    \
        FMA8(G##s##1, Vt.y);                                    \
        FMA8(G##s##2, Vt.z);                                    \
        FMA8(G##s##3, Vt.w);                                    \
    } while (0)

#define CONS(s)                                                 \
    do {                                                        \
        FMA8(G##s##0, V##s.x);                                  \
        FMA8(G##s##1, V##s.y);                                  \
        FMA8(G##s##2, V##s.z);                                  \
        FMA8(G##s##3, V##s.w);                                  \
    } while (0)

__global__ __launch_bounds__(256, 4) void spmm_kernel(
    const float* __restrict__ vals, const int* __restrict__ cols,
    const int* __restrict__ row_start, const uint32_t* __restrict__ st2,
    const float* __restrict__ proj, const float* __restrict__ res,
    float* __restrict__ out) {
    const int t = threadIdx.x;
    const int w = t >> 6;          // wave -> row within block
    const int l = t & 63;
    const int g = l >> 4;          // 4-nnz pack slot
    const int j = l & 15;          // batch slot: batches 8j..8j+7
    const int bp = (blockIdx.x & 7) * 256 + (blockIdx.x >> 3);
    const int r0 = bp * 4;
    const int r  = r0 + w;

    const int ks = row_start[r];
    const int ke = row_start[r + 1];
    const int ka = min(ke, (ks + 3) & ~3);   // 16B-align start
    const int U  = (ke - ka) >> 4;           // full 16-nnz units
    const int ts = ka + (U << 4);            // tail start (<16 left)

    const char* stb = (const char*)st2;
    const uint32_t joff = (uint32_t)j << 4;
    float a0 = 0, a1 = 0, a2 = 0, a3 = 0, a4 = 0, a5 = 0, a6 = 0, a7 = 0;

    if (ks < ka) {
        const int kk = ks + g;
        int c = 0; float v = 0.0f;
        if (kk < ka) { c = cols[kk]; v = vals[kk]; }
        const uint4 G = *(const uint4*)(stb + (((uint32_t)c << 8) + joff));
        FMA8(G, v);
    }
    if (ts < ke) {
#pragma unroll
        for (int i2 = 0; i2 < 4; ++i2) {
            const int kk = ts + 4 * i2 + g;
            int c = 0; float v = 0.0f;
            if (kk < ke) { c = cols[kk]; v = vals[kk]; }
            const uint4 G = *(const uint4*)(stb + (((uint32_t)c << 8) + joff));
            FMA8(G, v);
        }
    }

    int4 CA, CB; float4 VA, VB;
    uint4 GA0, GA1, GA2, GA3, GB0, GB1, GB2, GB3;

    if (U >= 4) {
        LOADCV(A, 0);
        LOADCV(B, 1);
        LOADG(A);
        int i = 0;
        for (; i + 4 <= U; i += 2) {
            {
                const float4 Vt = VA;
                LOADCV(A, i + 2);
                LOADG(B);
                CONS_T(A);
            }
            {
                const float4 Vt = VB;
                LOADCV(B, i + 3);
                LOADG(A);
                CONS_T(B);
            }
        }
        LOADG(B);
        if (i + 2 < U) {
            const float4 Vt = VA;
            LOADCV(A, i + 2);
            CONS_T(A);
            LOADG(A);
            CONS(B);
            CONS(A);
        } else {
            CONS(A);
            CONS(B);
        }
    } else {
        for (int u = 0; u < U; ++u) { LOADCV(A, u); LOADG(A); CONS(A); }
    }

    a0 += __shfl_xor(a0, 16, 64); a0 += __shfl_xor(a0, 32, 64);
    a1 += __shfl_xor(a1, 16, 64); a1 += __shfl_xor(a1, 32, 64);
    a2 += __shfl_xor(a2, 16, 64); a2 += __shfl_xor(a2, 32, 64);
    a3 += __shfl_xor(a3, 16, 64); a3 += __shfl_xor(a3, 32, 64);
    a4 += __shfl_xor(a4, 16, 64); a4 += __shfl_xor(a4, 32, 64);
    a5 += __shfl_xor(a5, 16, 64); a5 += __shfl_xor(a5, 32, 64);
    a6 += __shfl_xor(a6, 16, 64); a6 += __shfl_xor(a6, 32, 64);
    a7 += __shfl_xor(a7, 16, 64); a7 += __shfl_xor(a7, 32, 64);

    __shared__ float ly[4][BATCH];
    if (l < 16) {
        *(float4*)&ly[w][8 * j + 0] = make_float4(a0, a1, a2, a3);
        *(float4*)&ly[w][8 * j + 4] = make_float4(a4, a5, a6, a7);
    }
    __syncthreads();
    if (t < BATCH) {
        const int b = t;
        const size_t oi = (size_t)b * RES_DIM + r0;
        const float4 pj = *(const float4*)(proj + oi);
        const float4 rs = *(const float4*)(res + oi);
        float4 o;
        o.x = LEAK * fast_tanh(ly[0][b] + pj.x + BIAS) + (1.0f - LEAK) * rs.x;
        o.y = LEAK * fast_tanh(ly[1][b] + pj.y + BIAS) + (1.0f - LEAK) * rs.y;
        o.z = LEAK * fast_tanh(ly[2][b] + pj.z + BIAS) + (1.0f - LEAK) * rs.z;
        o.w = LEAK * fast_tanh(ly[3][b] + pj.w + BIAS) + (1.0f - LEAK) * rs.w;
        *(float4*)(out + oi) = o;
    }
}

// ---------------------------------------------------------------------------
extern "C" void kernel_launch(void* const* d_in, const int* in_sizes, int n_in,
                              void* d_out, int out_size, void* d_ws, size_t ws_size,
                              hipStream_t stream) {
    const float* proj      = (const float*)d_in[0];
    const float* res_state = (const float*)d_in[1];
    const float* wr_vals   = (const float*)d_in[2];
    const int*   wr_rows   = (const int*)d_in[3];
    const int*   wr_cols   = (const int*)d_in[4];
    float*       out       = (float*)d_out;

    uint8_t*  ws        = (uint8_t*)d_ws;
    uint32_t* st2       = (uint32_t*)ws;
    int*      row_start = (int*)(ws + 2097152);

    prep_kernel<<<CONV_BLOCKS + BND_BLOCKS, 256, 0, stream>>>(
        res_state, st2, wr_rows, row_start);

    // MEASUREMENT ROUND: spmm launched 5x (idempotent — each launch writes the
    // identical final `out`). dur9 = F + 5S; with round-8's F + S = 34.3 this
    // yields S = (dur9 - 34.3)/4. Round 10 reverts to a single launch.
    for (int rep = 0; rep < 5; ++rep) {
        spmm_kernel<<<RES_DIM / 4, 256, 0, stream>>>(
            wr_vals, wr_cols, row_start, st2, proj, res_state, out);
    }
}

// Round 11
// 109.643 us; speedup vs baseline: 1.1407x; 1.1407x over previous
//
#include <hip/hip_runtime.h>
#include <hip/hip_cooperative_groups.h>
#include <stdint.h>

namespace cg = cooperative_groups;

#define RES_DIM 8192
#define BATCH   128
#define NNZ     1342177
#define LEAK    0.6f
#define BIAS    1.6f

#define CONV_BLOCKS 1024                          // (RES_DIM/32) * (BATCH/32)
#define BND_THREADS ((NNZ + 3) / 4)               // 335545
#define BND_BLOCKS  ((BND_THREADS + 255) / 256)   // 1311

// ---------------------------------------------------------------------------
// helpers
// ---------------------------------------------------------------------------
__device__ __forceinline__ float fast_tanh(float x) {
    float e = __expf(2.0f * x);
    return 1.0f - 2.0f / (e + 1.0f);
}

__device__ __forceinline__ uint32_t f32_to_bf16_rne(float f) {
    uint32_t u = __float_as_uint(f);
    return (u + 0x7fffu + ((u >> 16) & 1u)) >> 16;
}

// ---------------------------------------------------------------------------
// shared macros (spmm inner loop)
// ---------------------------------------------------------------------------
#define FMA8(G, v)                                              \
    do {                                                        \
        a0 = fmaf(v, __uint_as_float((G).x << 16), a0);         \
        a1 = fmaf(v, __uint_as_float((G).x & 0xffff0000u), a1); \
        a2 = fmaf(v, __uint_as_float((G).y << 16), a2);         \
        a3 = fmaf(v, __uint_as_float((G).y & 0xffff0000u), a3); \
        a4 = fmaf(v, __uint_as_float((G).z << 16), a4);         \
        a5 = fmaf(v, __uint_as_float((G).z & 0xffff0000u), a5); \
        a6 = fmaf(v, __uint_as_float((G).w << 16), a6);         \
        a7 = fmaf(v, __uint_as_float((G).w & 0xffff0000u), a7); \
    } while (0)

#define LOADCV(s, u)                                            \
    do {                                                        \
        const int base_ = ka + ((u) << 4) + 4 * g;              \
        C##s = *(const int4*)(cols + base_);                    \
        V##s = *(const float4*)(vals + base_);                  \
    } while (0)

#define LOADG(s)                                                              \
    do {                                                                      \
        G##s##0 = *(const uint4*)(stb + (((uint32_t)C##s.x << 8) + joff));    \
        G##s##1 = *(const uint4*)(stb + (((uint32_t)C##s.y << 8) + joff));    \
        G##s##2 = *(const uint4*)(stb + (((uint32_t)C##s.z << 8) + joff));    \
        G##s##3 = *(const uint4*)(stb + (((uint32_t)C##s.w << 8) + joff));    \
    } while (0)

#define CONS_T(s)                                               \
    do {                                                        \
        FMA8(G##s##0, Vt.x);                                    \
        FMA8(G##s##1, Vt.y);                                    \
        FMA8(G##s##2, Vt.z);                                    \
        FMA8(G##s##3, Vt.w);                                    \
    } while (0)

#define CONS(s)                                                 \
    do {                                                        \
        FMA8(G##s##0, V##s.x);                                  \
        FMA8(G##s##1, V##s.y);                                  \
        FMA8(G##s##2, V##s.z);                                  \
        FMA8(G##s##3, V##s.w);                                  \
    } while (0)

// Computes one row's y partials into a0..a7 (declared by caller).
#define SPMM_ROW_BODY()                                                        \
    do {                                                                       \
        if (ks < ka) {                                                         \
            const int kk = ks + g;                                             \
            int c = 0; float v = 0.0f;                                         \
            if (kk < ka) { c = cols[kk]; v = vals[kk]; }                       \
            const uint4 G = *(const uint4*)(stb + (((uint32_t)c << 8) + joff));\
            FMA8(G, v);                                                        \
        }                                                                      \
        if (ts < ke) {                                                         \
            _Pragma("unroll")                                                  \
            for (int i2 = 0; i2 < 4; ++i2) {                                   \
                const int kk = ts + 4 * i2 + g;                                \
                int c = 0; float v = 0.0f;                                     \
                if (kk < ke) { c = cols[kk]; v = vals[kk]; }                   \
                const uint4 G = *(const uint4*)(stb + (((uint32_t)c << 8) + joff));\
                FMA8(G, v);                                                    \
            }                                                                  \
        }                                                                      \
        int4 CA, CB; float4 VA, VB;                                            \
        uint4 GA0, GA1, GA2, GA3, GB0, GB1, GB2, GB3;                          \
        if (U >= 4) {                                                          \
            LOADCV(A, 0);                                                      \
            LOADCV(B, 1);                                                      \
            LOADG(A);                                                          \
            int i = 0;                                                         \
            for (; i + 4 <= U; i += 2) {                                       \
                {                                                              \
                    const float4 Vt = VA;                                      \
                    LOADCV(A, i + 2);                                          \
                    LOADG(B);                                                  \
                    CONS_T(A);                                                 \
                }                                                              \
                {                                                              \
                    const float4 Vt = VB;                                      \
                    LOADCV(B, i + 3);                                          \
                    LOADG(A);                                                  \
                    CONS_T(B);                                                 \
                }                                                              \
            }                                                                  \
            LOADG(B);                                                          \
            if (i + 2 < U) {                                                   \
                const float4 Vt = VA;                                          \
                LOADCV(A, i + 2);                                              \
                CONS_T(A);                                                     \
                LOADG(A);                                                      \
                CONS(B);                                                       \
                CONS(A);                                                       \
            } else {                                                           \
                CONS(A);                                                       \
                CONS(B);                                                       \
            }                                                                  \
        } else {                                                               \
            for (int u = 0; u < U; ++u) { LOADCV(A, u); LOADG(A); CONS(A); }   \
        }                                                                      \
        a0 += __shfl_xor(a0, 16, 64); a0 += __shfl_xor(a0, 32, 64);            \
        a1 += __shfl_xor(a1, 16, 64); a1 += __shfl_xor(a1, 32, 64);            \
        a2 += __shfl_xor(a2, 16, 64); a2 += __shfl_xor(a2, 32, 64);            \
        a3 += __shfl_xor(a3, 16, 64); a3 += __shfl_xor(a3, 32, 64);            \
        a4 += __shfl_xor(a4, 16, 64); a4 += __shfl_xor(a4, 32, 64);            \
        a5 += __shfl_xor(a5, 16, 64); a5 += __shfl_xor(a5, 32, 64);            \
        a6 += __shfl_xor(a6, 16, 64); a6 += __shfl_xor(a6, 32, 64);            \
        a7 += __shfl_xor(a7, 16, 64); a7 += __shfl_xor(a7, 32, 64);            \
    } while (0)

// ---------------------------------------------------------------------------
// FALLBACK path (round-8 proven kernels)
// ---------------------------------------------------------------------------
__global__ __launch_bounds__(256) void prep_kernel(
    const float* __restrict__ in, uint32_t* __restrict__ st2,
    const int* __restrict__ rows, int* __restrict__ row_start) {
    if (blockIdx.x < CONV_BLOCKS) {
        __shared__ float tile[32][33];
        const int bx = blockIdx.x & 255;
        const int by = blockIdx.x >> 8;
        const int tx = threadIdx.x & 31, ty = threadIdx.x >> 5;
        const int r0 = bx * 32, b0 = by * 32;
#pragma unroll
        for (int j = 0; j < 32; j += 8)
            tile[ty + j][tx] = in[(size_t)(b0 + ty + j) * RES_DIM + r0 + tx];
        __syncthreads();
#pragma unroll
        for (int i = threadIdx.x; i < 512; i += 256) {
            int rl = i >> 4, pl = i & 15;
            uint32_t lo = f32_to_bf16_rne(tile[2 * pl + 0][rl]);
            uint32_t hi = f32_to_bf16_rne(tile[2 * pl + 1][rl]);
            st2[(size_t)(r0 + rl) * 64 + (b0 >> 1) + pl] = lo | (hi << 16);
        }
    } else {
        const int t  = (blockIdx.x - CONV_BLOCKS) * 256 + threadIdx.x;
        const int k4 = t * 4;
        if (k4 >= NNZ) return;
        if (k4 + 4 <= NNZ) {
            const int4 R = *(const int4*)(rows + k4);
            if (k4 == 0)
                for (int r = 0; r <= R.x; ++r) row_start[r] = 0;
            const int rn = rows[k4 + 4];
            for (int r = R.x + 1; r <= R.y; ++r) row_start[r] = k4 + 1;
            for (int r = R.y + 1; r <= R.z; ++r) row_start[r] = k4 + 2;
            for (int r = R.z + 1; r <= R.w; ++r) row_start[r] = k4 + 3;
            for (int r = R.w + 1; r <= rn;  ++r) row_start[r] = k4 + 4;
        } else {
            const int r1 = rows[k4];
            for (int r = r1 + 1; r <= RES_DIM; ++r) row_start[r] = NNZ;
        }
    }
}

__global__ __launch_bounds__(256, 4) void spmm_fb_kernel(
    const float* __restrict__ vals, const int* __restrict__ cols,
    const int* __restrict__ row_start, const uint32_t* __restrict__ st2,
    const float* __restrict__ proj, const float* __restrict__ res,
    float* __restrict__ out) {
    const int t = threadIdx.x;
    const int w = t >> 6;
    const int l = t & 63;
    const int g = l >> 4;
    const int j = l & 15;
    const int bp = (blockIdx.x & 7) * 256 + (blockIdx.x >> 3);
    const int r0 = bp * 4;
    const int r  = r0 + w;

    const int ks = row_start[r];
    const int ke = row_start[r + 1];
    const int ka = min(ke, (ks + 3) & ~3);
    const int U  = (ke - ka) >> 4;
    const int ts = ka + (U << 4);

    const char* stb = (const char*)st2;
    const uint32_t joff = (uint32_t)j << 4;
    float a0 = 0, a1 = 0, a2 = 0, a3 = 0, a4 = 0, a5 = 0, a6 = 0, a7 = 0;

    SPMM_ROW_BODY();

    __shared__ float ly[4][BATCH];
    if (l < 16) {
        *(float4*)&ly[w][8 * j + 0] = make_float4(a0, a1, a2, a3);
        *(float4*)&ly[w][8 * j + 4] = make_float4(a4, a5, a6, a7);
    }
    __syncthreads();
    if (t < BATCH) {
        const int b = t;
        const size_t oi = (size_t)b * RES_DIM + r0;
        const float4 pj = *(const float4*)(proj + oi);
        const float4 rs = *(const float4*)(res + oi);
        float4 o;
        o.x = LEAK * fast_tanh(ly[0][b] + pj.x + BIAS) + (1.0f - LEAK) * rs.x;
        o.y = LEAK * fast_tanh(ly[1][b] + pj.y + BIAS) + (1.0f - LEAK) * rs.y;
        o.z = LEAK * fast_tanh(ly[2][b] + pj.z + BIAS) + (1.0f - LEAK) * rs.z;
        o.w = LEAK * fast_tanh(ly[3][b] + pj.w + BIAS) + (1.0f - LEAK) * rs.w;
        *(float4*)(out + oi) = o;
    }
}

// ---------------------------------------------------------------------------
// COOPERATIVE fused kernel. Grid-strided phases: any grid >= 8 is correct;
// host sizes the grid to min(1024, occupancy * CUs) so the launch is legal.
// ---------------------------------------------------------------------------
__global__ __launch_bounds__(256, 4) void fused_kernel(
    const float* __restrict__ proj, const float* __restrict__ res,
    const float* __restrict__ vals, const int* __restrict__ rows,
    const int* __restrict__ cols, uint32_t* __restrict__ st2,
    int* __restrict__ row_start, float* __restrict__ out) {

    __shared__ float smem[32 * 33];          // conv tile; reused as ly[8][128]
    const int tid = threadIdx.x;

    // ---- Phase 1a: conv (1024 virtual tiles, grid-strided) ----
    {
        float (*tile)[33] = (float(*)[33])smem;
        const int tx = tid & 31, ty = tid >> 5;   // 32x8
        for (int vt = blockIdx.x; vt < 1024; vt += gridDim.x) {
            const int r0 = (vt & 255) * 32, b0 = (vt >> 8) * 32;
            __syncthreads();                 // smem reuse guard
#pragma unroll
            for (int j = 0; j < 32; j += 8)
                tile[ty + j][tx] = res[(size_t)(b0 + ty + j) * RES_DIM + r0 + tx];
            __syncthreads();
#pragma unroll
            for (int i = tid; i < 512; i += 256) {
                int rl = i >> 4, pl = i & 15;
                uint32_t lo = f32_to_bf16_rne(tile[2 * pl + 0][rl]);
                uint32_t hi = f32_to_bf16_rne(tile[2 * pl + 1][rl]);
                st2[(size_t)(r0 + rl) * 64 + (b0 >> 1) + pl] = lo | (hi << 16);
            }
        }
    }

    // ---- Phase 1b: rowptr boundary detect (8 nnz per virtual thread) ----
    {
        const int tcount = gridDim.x * 256;
        for (int vt = blockIdx.x * 256 + tid; vt * 8 < NNZ; vt += tcount) {
            const int k8 = vt * 8;
            int rprev = (k8 == 0) ? -1 : rows[k8 - 1];
            const int n = min(8, NNZ - k8);
            if (n == 8) {
                const int4 Ra = *(const int4*)(rows + k8);
                const int4 Rb = *(const int4*)(rows + k8 + 4);
                const int rr[8] = {Ra.x, Ra.y, Ra.z, Ra.w, Rb.x, Rb.y, Rb.z, Rb.w};
#pragma unroll
                for (int i = 0; i < 8; ++i) {
                    for (int q = rprev + 1; q <= rr[i]; ++q) row_start[q] = k8 + i;
                    rprev = rr[i];
                }
            } else {
                for (int i = 0; i < n; ++i) {
                    const int rc = rows[k8 + i];
                    for (int q = rprev + 1; q <= rc; ++q) row_start[q] = k8 + i;
                    rprev = rc;
                }
            }
            if (k8 + 8 >= NNZ)
                for (int q = rprev + 1; q <= RES_DIM; ++q) row_start[q] = NNZ;
        }
    }

    cg::this_grid().sync();

    // ---- Phase 2+3: spmm (8 rows per virtual group) + fused epilogue ----
    const int w = tid >> 6;
    const int l = tid & 63;
    const int g = l >> 4;
    const int j = l & 15;
    const char* stb = (const char*)st2;
    const uint32_t joff = (uint32_t)j << 4;
    float (*ly)[BATCH] = (float(*)[BATCH])smem;

    for (int vb = blockIdx.x; vb < 1024; vb += gridDim.x) {
        const int bp = (vb & 7) * 128 + (vb >> 3);   // XCD-bijective over 1024
        const int r0 = bp * 8;
        __syncthreads();                             // ly reuse guard

#pragma unroll 1
        for (int half = 0; half < 2; ++half) {
            const int r = r0 + half * 4 + w;
            const int ks = row_start[r];
            const int ke = row_start[r + 1];
            const int ka = min(ke, (ks + 3) & ~3);
            const int U  = (ke - ka) >> 4;
            const int ts = ka + (U << 4);

            float a0 = 0, a1 = 0, a2 = 0, a3 = 0, a4 = 0, a5 = 0, a6 = 0, a7 = 0;
            SPMM_ROW_BODY();

            if (l < 16) {
                *(float4*)&ly[half * 4 + w][8 * j + 0] = make_float4(a0, a1, a2, a3);
                *(float4*)&ly[half * 4 + w][8 * j + 4] = make_float4(a4, a5, a6, a7);
            }
        }
        __syncthreads();
        if (tid < BATCH) {
            const int b = tid;
            const size_t oi = (size_t)b * RES_DIM + r0;
            const float4 pj0 = *(const float4*)(proj + oi);
            const float4 pj1 = *(const float4*)(proj + oi + 4);
            const float4 rs0 = *(const float4*)(res + oi);
            const float4 rs1 = *(const float4*)(res + oi + 4);
            float4 o0, o1;
            o0.x = LEAK * fast_tanh(ly[0][b] + pj0.x + BIAS) + (1.0f - LEAK) * rs0.x;
            o0.y = LEAK * fast_tanh(ly[1][b] + pj0.y + BIAS) + (1.0f - LEAK) * rs0.y;
            o0.z = LEAK * fast_tanh(ly[2][b] + pj0.z + BIAS) + (1.0f - LEAK) * rs0.z;
            o0.w = LEAK * fast_tanh(ly[3][b] + pj0.w + BIAS) + (1.0f - LEAK) * rs0.w;
            o1.x = LEAK * fast_tanh(ly[4][b] + pj1.x + BIAS) + (1.0f - LEAK) * rs1.x;
            o1.y = LEAK * fast_tanh(ly[5][b] + pj1.y + BIAS) + (1.0f - LEAK) * rs1.y;
            o1.z = LEAK * fast_tanh(ly[6][b] + pj1.z + BIAS) + (1.0f - LEAK) * rs1.z;
            o1.w = LEAK * fast_tanh(ly[7][b] + pj1.w + BIAS) + (1.0f - LEAK) * rs1.w;
            *(float4*)(out + oi + 0) = o0;
            *(float4*)(out + oi + 4) = o1;
        }
    }
}

// ---------------------------------------------------------------------------
extern "C" void kernel_launch(void* const* d_in, const int* in_sizes, int n_in,
                              void* d_out, int out_size, void* d_ws, size_t ws_size,
                              hipStream_t stream) {
    const float* proj      = (const float*)d_in[0];
    const float* res_state = (const float*)d_in[1];
    const float* wr_vals   = (const float*)d_in[2];
    const int*   wr_rows   = (const int*)d_in[3];
    const int*   wr_cols   = (const int*)d_in[4];
    float*       out       = (float*)d_out;

    uint8_t*  ws        = (uint8_t*)d_ws;
    uint32_t* st2       = (uint32_t*)ws;
    int*      row_start = (int*)(ws + 2097152);

    // Size the cooperative grid from actual occupancy (host-only queries;
    // they execute at capture time, not during graph replay).
    int nCU = 256, maxB = 0;
    {
        int dev = 0;
        if (hipGetDevice(&dev) == hipSuccess) {
            hipDeviceProp_t prop;
            if (hipGetDeviceProperties(&prop, dev) == hipSuccess &&
                prop.multiProcessorCount > 0)
                nCU = prop.multiProcessorCount;
        }
        (void)hipOccupancyMaxActiveBlocksPerMultiprocessor(
            &maxB, (const void*)fused_kernel, 256, 0);
    }
    long grid = (long)maxB * nCU;
    if (grid > 1024) grid = 1024;

    hipError_t err = hipErrorUnknown;
    if (grid >= 8) {
        void* args[] = {
            (void*)&proj, (void*)&res_state, (void*)&wr_vals, (void*)&wr_rows,
            (void*)&wr_cols, (void*)&st2, (void*)&row_start, (void*)&out,
        };
        err = hipLaunchCooperativeKernel((const void*)fused_kernel,
                                         dim3((uint32_t)grid), dim3(256),
                                         args, 0, stream);
    }
    if (err != hipSuccess) {
        // Proven round-8 fallback: identical output, two launches.
        prep_kernel<<<CONV_BLOCKS + BND_BLOCKS, 256, 0, stream>>>(
            res_state, st2, wr_rows, row_start);
        spmm_fb_kernel<<<RES_DIM / 4, 256, 0, stream>>>(
            wr_vals, wr_cols, row_start, st2, proj, res_state, out);
    }
}

// Round 12
// 43.109 us; speedup vs baseline: 2.9013x; 2.5434x over previous
//
#include <hip/hip_runtime.h>
#include <stdint.h>

#define RES_DIM 8192
#define BATCH   128
#define NNZ     1342177
#define LEAK    0.6f
#define BIAS    1.6f

#define CONV_BLOCKS 1024                 // (RES_DIM/32) * (BATCH/32)

// ---------------------------------------------------------------------------
// helpers
// ---------------------------------------------------------------------------
__device__ __forceinline__ float fast_tanh(float x) {
    float e = __expf(2.0f * x);
    return 1.0f - 2.0f / (e + 1.0f);
}

__device__ __forceinline__ uint32_t f32_to_bf16_rne(float f) {
    uint32_t u = __float_as_uint(f);
    return (u + 0x7fffu + ((u >> 16) & 1u)) >> 16;
}

// ---------------------------------------------------------------------------
// Kernel 1: conv only — res_state [B][R] f32 -> st2 [R][64] u32
//           (u32 p packs bf16 of batches (2p, 2p+1), lo = even batch)
// ---------------------------------------------------------------------------
__global__ __launch_bounds__(256) void prep_kernel(
    const float* __restrict__ in, uint32_t* __restrict__ st2) {
    __shared__ float tile[32][33];
    const int bx = blockIdx.x & 255;     // r-tile
    const int by = blockIdx.x >> 8;      // b-tile
    const int tx = threadIdx.x & 31, ty = threadIdx.x >> 5;  // 32x8
    const int r0 = bx * 32, b0 = by * 32;
#pragma unroll
    for (int j = 0; j < 32; j += 8)
        tile[ty + j][tx] = in[(size_t)(b0 + ty + j) * RES_DIM + r0 + tx];
    __syncthreads();
#pragma unroll
    for (int i = threadIdx.x; i < 512; i += 256) {   // 32 r x 16 pairs
        int rl = i >> 4, pl = i & 15;
        uint32_t lo = f32_to_bf16_rne(tile[2 * pl + 0][rl]);
        uint32_t hi = f32_to_bf16_rne(tile[2 * pl + 1][rl]);
        st2[(size_t)(r0 + rl) * 64 + (b0 >> 1) + pl] = lo | (hi << 16);
    }
}

// ---------------------------------------------------------------------------
// Kernel 2: spmm + fused epilogue (round-8 proven structure).
// One wave per row, 4 rows/block. Row boundaries found per-block by 5-thread
// binary search over the SORTED rows[] (replaces the rowptr prep pass; the
// ~21-step dependent-load chain hides under co-resident waves' gathers).
// 16-lane group g owns 4 contiguous nnz (one int4/float4 broadcast pack);
// lane j = l&15 holds batches 8j..8j+7 (uint4 = 8 bf16 per gather).
// Phase-split 2-slot pipeline; drain stashes Vt before slot reuse.
// ---------------------------------------------------------------------------
#define FMA8(G, v)                                              \
    do {                                                        \
        a0 = fmaf(v, __uint_as_float((G).x << 16), a0);         \
        a1 = fmaf(v, __uint_as_float((G).x & 0xffff0000u), a1); \
        a2 = fmaf(v, __uint_as_float((G).y << 16), a2);         \
        a3 = fmaf(v, __uint_as_float((G).y & 0xffff0000u), a3); \
        a4 = fmaf(v, __uint_as_float((G).z << 16), a4);         \
        a5 = fmaf(v, __uint_as_float((G).z & 0xffff0000u), a5); \
        a6 = fmaf(v, __uint_as_float((G).w << 16), a6);         \
        a7 = fmaf(v, __uint_as_float((G).w & 0xffff0000u), a7); \
    } while (0)

#define LOADCV(s, u)                                            \
    do {                                                        \
        const int base_ = ka + ((u) << 4) + 4 * g;              \
        C##s = *(const int4*)(cols + base_);                    \
        V##s = *(const float4*)(vals + base_);                  \
    } while (0)

#define LOADG(s)                                                              \
    do {                                                                      \
        G##s##0 = *(const uint4*)(stb + (((uint32_t)C##s.x << 8) + joff));    \
        G##s##1 = *(const uint4*)(stb + (((uint32_t)C##s.y << 8) + joff));    \
        G##s##2 = *(const uint4*)(stb + (((uint32_t)C##s.z << 8) + joff));    \
        G##s##3 = *(const uint4*)(stb + (((uint32_t)C##s.w << 8) + joff));    \
    } while (0)

#define CONS_T(s)                                               \
    do {                                                        \
        FMA8(G##s##0, Vt.x);                                    \
        FMA8(G##s##1, Vt.y);                                    \
        FMA8(G##s##2, Vt.z);                                    \
        FMA8(G##s##3, Vt.w);                                    \
    } while (0)

#define CONS(s)                                                 \
    do {                                                        \
        FMA8(G##s##0, V##s.x);                                  \
        FMA8(G##s##1, V##s.y);                                  \
        FMA8(G##s##2, V##s.z);                                  \
        FMA8(G##s##3, V##s.w);                                  \
    } while (0)

__global__ __launch_bounds__(256, 4) void spmm_kernel(
    const float* __restrict__ vals, const int* __restrict__ cols,
    const int* __restrict__ rows, const uint32_t* __restrict__ st2,
    const float* __restrict__ proj, const float* __restrict__ res,
    float* __restrict__ out) {
    const int t = threadIdx.x;
    const int w = t >> 6;          // wave -> row within block
    const int l = t & 63;
    const int g = l >> 4;          // 4-nnz pack slot
    const int j = l & 15;          // batch slot: batches 8j..8j+7
    // XCD-bijective swizzle over 2048 blocks (2048 = 8 * 256)
    const int bp = (blockIdx.x & 7) * 256 + (blockIdx.x >> 3);
    const int r0 = bp * 4;

    // ---- per-block row boundaries: 5-thread binary search (lower_bound) ----
    __shared__ int rsb[5];
    if (t < 5) {
        const int target = r0 + t;
        int lo = 0, hi = NNZ;
        while (lo < hi) {
            const int mid = (lo + hi) >> 1;
            if (rows[mid] < target) lo = mid + 1; else hi = mid;
        }
        rsb[t] = lo;
    }
    __syncthreads();
    const int ks = rsb[w];
    const int ke = rsb[w + 1];
    const int ka = min(ke, (ks + 3) & ~3);   // 16B-align start
    const int U  = (ke - ka) >> 4;           // full 16-nnz units
    const int ts = ka + (U << 4);            // tail start (<16 left)

    const char* stb = (const char*)st2;
    const uint32_t joff = (uint32_t)j << 4;
    float a0 = 0, a1 = 0, a2 = 0, a3 = 0, a4 = 0, a5 = 0, a6 = 0, a7 = 0;

    // head (<=3 nnz, unaligned)
    if (ks < ka) {
        const int kk = ks + g;
        int c = 0; float v = 0.0f;
        if (kk < ka) { c = cols[kk]; v = vals[kk]; }
        const uint4 G = *(const uint4*)(stb + (((uint32_t)c << 8) + joff));
        FMA8(G, v);
    }
    // tail (<=15 nnz)
    if (ts < ke) {
#pragma unroll
        for (int i2 = 0; i2 < 4; ++i2) {
            const int kk = ts + 4 * i2 + g;
            int c = 0; float v = 0.0f;
            if (kk < ke) { c = cols[kk]; v = vals[kk]; }
            const uint4 G = *(const uint4*)(stb + (((uint32_t)c << 8) + joff));
            FMA8(G, v);
        }
    }

    // ---- phase-split pipelined main loop ----
    int4 CA, CB; float4 VA, VB;
    uint4 GA0, GA1, GA2, GA3, GB0, GB1, GB2, GB3;

    if (U >= 4) {
        LOADCV(A, 0);
        LOADCV(B, 1);
        LOADG(A);                              // unit 0
        int i = 0;
        for (; i + 4 <= U; i += 2) {
            {   // unit i (slot A); prefetch CV(i+2), G(i+1)
                const float4 Vt = VA;
                LOADCV(A, i + 2);
                LOADG(B);                      // unit i+1, CB loaded 1 iter ago
                CONS_T(A);
            }
            {   // unit i+1 (slot B); prefetch CV(i+3), G(i+2)
                const float4 Vt = VB;
                LOADCV(B, i + 3);
                LOADG(A);                      // unit i+2, CA loaded above
                CONS_T(B);
            }
        }
        // exit: GA/VA = unit i (ready); CB/VB = unit i+1 (cols ready)
        LOADG(B);                              // unit i+1 gathers
        if (i + 2 < U) {                       // 3 units left: i, i+1, i+2
            const float4 Vt = VA;              // stash BEFORE clobbering slot A
            LOADCV(A, i + 2);
            CONS_T(A);                         // unit i
            LOADG(A);                          // unit i+2
            CONS(B);                           // unit i+1
            CONS(A);                           // unit i+2
        } else {                               // 2 units left: i, i+1
            CONS(A);
            CONS(B);
        }
    } else {
        for (int u = 0; u < U; ++u) { LOADCV(A, u); LOADG(A); CONS(A); }
    }

    // combine the 4 nnz-groups within the wave
    a0 += __shfl_xor(a0, 16, 64); a0 += __shfl_xor(a0, 32, 64);
    a1 += __shfl_xor(a1, 16, 64); a1 += __shfl_xor(a1, 32, 64);
    a2 += __shfl_xor(a2, 16, 64); a2 += __shfl_xor(a2, 32, 64);
    a3 += __shfl_xor(a3, 16, 64); a3 += __shfl_xor(a3, 32, 64);
    a4 += __shfl_xor(a4, 16, 64); a4 += __shfl_xor(a4, 32, 64);
    a5 += __shfl_xor(a5, 16, 64); a5 += __shfl_xor(a5, 32, 64);
    a6 += __shfl_xor(a6, 16, 64); a6 += __shfl_xor(a6, 32, 64);
    a7 += __shfl_xor(a7, 16, 64); a7 += __shfl_xor(a7, 32, 64);

    // stage y[4 rows][128 b] in LDS, then fused tanh/leak epilogue
    __shared__ float ly[4][BATCH];
    if (l < 16) {
        *(float4*)&ly[w][8 * j + 0] = make_float4(a0, a1, a2, a3);
        *(float4*)&ly[w][8 * j + 4] = make_float4(a4, a5, a6, a7);
    }
    __syncthreads();
    if (t < BATCH) {
        const int b = t;
        const size_t oi = (size_t)b * RES_DIM + r0;
        const float4 pj = *(const float4*)(proj + oi);
        const float4 rs = *(const float4*)(res + oi);
        float4 o;
        o.x = LEAK * fast_tanh(ly[0][b] + pj.x + BIAS) + (1.0f - LEAK) * rs.x;
        o.y = LEAK * fast_tanh(ly[1][b] + pj.y + BIAS) + (1.0f - LEAK) * rs.y;
        o.z = LEAK * fast_tanh(ly[2][b] + pj.z + BIAS) + (1.0f - LEAK) * rs.z;
        o.w = LEAK * fast_tanh(ly[3][b] + pj.w + BIAS) + (1.0f - LEAK) * rs.w;
        *(float4*)(out + oi) = o;
    }
}

// ---------------------------------------------------------------------------
extern "C" void kernel_launch(void* const* d_in, const int* in_sizes, int n_in,
                              void* d_out, int out_size, void* d_ws, size_t ws_size,
                              hipStream_t stream) {
    const float* proj      = (const float*)d_in[0];
    const float* res_state = (const float*)d_in[1];
    const float* wr_vals   = (const float*)d_in[2];
    const int*   wr_rows   = (const int*)d_in[3];
    const int*   wr_cols   = (const int*)d_in[4];
    float*       out       = (float*)d_out;

    // ws layout: st2 (2 MB)
    uint32_t* st2 = (uint32_t*)d_ws;

    prep_kernel<<<CONV_BLOCKS, 256, 0, stream>>>(res_state, st2);

    spmm_kernel<<<RES_DIM / 4, 256, 0, stream>>>(
        wr_vals, wr_cols, wr_rows, st2, proj, res_state, out);
}